// Round 5
// baseline (324.754 us; speedup 1.0000x reference)
//
#include <hip/hip_runtime.h>
#include <stdint.h>

#define M_DIM 32768
#define K_DIM 1024
#define N_DIM 1024

typedef int v4i __attribute__((ext_vector_type(4)));

// ---------------- kernel 1: fused minmax partials + w transpose ----------------
// blocks 0..1023   : per-block min/max partials over x (32 float4 iters/thread)
// blocks 1024..2047: transpose w [K,N] int32 -> wt [N,K] int8 (32x32 tiles)
__global__ void k_prep(const float* __restrict__ x,
                       float* __restrict__ pmin, float* __restrict__ pmax,
                       const int* __restrict__ w, int8_t* __restrict__ wt) {
    int t = threadIdx.x;
    if (blockIdx.x < 1024) {
        long gid = (long)blockIdx.x * 256 + t;
        const float4* x4 = (const float4*)x;
        const long n4 = (long)M_DIM * K_DIM / 4;  // 8M, exactly 32 iters/thread
        float mn = INFINITY, mx = -INFINITY;
#pragma unroll 4
        for (long i = gid; i < n4; i += 1024 * 256) {
            float4 v = x4[i];
            mn = fminf(mn, fminf(fminf(v.x, v.y), fminf(v.z, v.w)));
            mx = fmaxf(mx, fmaxf(fmaxf(v.x, v.y), fmaxf(v.z, v.w)));
        }
        __shared__ float smn[256], smx[256];
        smn[t] = mn; smx[t] = mx;
        __syncthreads();
        for (int s = 128; s > 0; s >>= 1) {
            if (t < s) {
                smn[t] = fminf(smn[t], smn[t + s]);
                smx[t] = fmaxf(smx[t], smx[t + s]);
            }
            __syncthreads();
        }
        if (t == 0) { pmin[blockIdx.x] = smn[0]; pmax[blockIdx.x] = smx[0]; }
    } else {
        __shared__ int8_t tile[32][33];
        int b = blockIdx.x - 1024;          // 0..1023
        int bn = (b & 31) * 32;             // N tile
        int bk = (b >> 5) * 32;             // K tile
        int tx = t & 31, ty = t >> 5;       // 32x8
#pragma unroll
        for (int i = 0; i < 32; i += 8)
            tile[ty + i][tx] = (int8_t)w[(long)(bk + ty + i) * N_DIM + bn + tx];
        __syncthreads();
#pragma unroll
        for (int i = 0; i < 32; i += 8)
            wt[(long)(bn + ty + i) * K_DIM + bk + tx] = tile[tx][ty + i];
    }
}

// ---------------- quantize helper (IEEE div + rintf = RTNE, matches jnp) ----------------
__device__ __forceinline__ unsigned q4(float4 v, float s, float zp) {
    int a = (int)fminf(fmaxf(rintf(v.x / s) + zp, -128.0f), 127.0f);
    int b = (int)fminf(fmaxf(rintf(v.y / s) + zp, -128.0f), 127.0f);
    int c = (int)fminf(fmaxf(rintf(v.z / s) + zp, -128.0f), 127.0f);
    int d = (int)fminf(fmaxf(rintf(v.w / s) + zp, -128.0f), 127.0f);
    return (a & 255) | ((b & 255) << 8) | ((c & 255) << 16) | ((d & 255) << 24);
}

// ---------------- kernel 2: FUSED quantize + int8 GEMM + dequant + bias ----------------
// 512 blocks x 512 threads. Block b owns output rows [b*64, b*64+64) x all 1024 cols.
// 1 resident block/CU (launch_bounds 512,2 -> 256 VGPR budget, no spills).
//   P0: re-reduce the 2x1024 min/max partials -> (s, zp), identical in every block
//       (min/max reduction is order-independent -> bit-exact vs reference).
//   P1: read own 64x1024 f32 x-panel (coalesced float4), quantize ONCE,
//       ds_write into 64 KB LDS panel, XOR-swizzled:
//         16B-quad q of row m stored at slot q ^ (m&7)
//       -> both the P1 writes and the P2 ds_read_b128 spread across all banks.
//   P2: BARRIER-FREE K-loop: A from LDS (read-only), B streamed from wt
//       (1 MB, L2-resident) global->regs, double-buffered one K-step ahead.
//       Waves never sync -> drift freely, latency self-hidden. 32 MFMA/wave/step.
//   P3: dequant + bias + store.
// xq is never materialized (saves 64 MB HBM round-trip + one kernel launch).
__global__ __launch_bounds__(512, 2) void k_gemm(
    const float* __restrict__ x, const int8_t* __restrict__ wt,
    const float* __restrict__ pmin, const float* __restrict__ pmax,
    const float* __restrict__ w_scales, const int* __restrict__ wsums,
    const float* __restrict__ bias, float* __restrict__ out) {
    __shared__ __align__(16) int8_t lds_a[64 * 1024];   // 64 KB quantized A panel
    __shared__ float red[2][512];                        // 4 KB reduce scratch

    const int t = threadIdx.x;
    const int m0 = blockIdx.x * 64;

    // ---- P0: partials -> (s, zp) ----
    red[0][t] = fminf(pmin[t], pmin[t + 512]);
    red[1][t] = fmaxf(pmax[t], pmax[t + 512]);
    __syncthreads();
    for (int ss = 256; ss > 0; ss >>= 1) {
        if (t < ss) {
            red[0][t] = fminf(red[0][t], red[0][t + ss]);
            red[1][t] = fmaxf(red[1][t], red[1][t + ss]);
        }
        __syncthreads();
    }
    const float min_neg = fminf(red[0][0], 0.0f);
    const float max_pos = fmaxf(red[1][0], 0.0f);
    float s = (max_pos - min_neg) / 255.0f;          // IEEE div, matches jnp
    s = fmaxf(s, 1.1920928955078125e-07f);           // np.finfo(f32).eps
    float zp = -128.0f - rintf(min_neg / s);         // rintf = RTNE = jnp.round
    zp = fminf(fmaxf(zp, -128.0f), 127.0f);

    // ---- P1: quantize own A panel into swizzled LDS ----
    // 16384 float4s; i = v*512 + t: row = i>>8 (256 float4/row), f4 = i&255.
    {
        const float4* xp = (const float4*)(x + (long)m0 * K_DIM);
#pragma unroll
        for (int v = 0; v < 32; v++) {
            int i = v * 512 + t;
            int row = i >> 8, f4 = i & 255;
            float4 val = xp[i];
            unsigned u = q4(val, s, zp);
            int quad = f4 >> 2;                  // 16B quad index 0..63
            int slot = quad ^ (row & 7);
            *(unsigned*)(lds_a + row * 1024 + slot * 16 + (f4 & 3) * 4) = u;
        }
    }
    __syncthreads();   // the ONLY barrier between phases; K-loop has none

    // ---- P2: K-loop ----
    const int wv = t >> 6, l = t & 63, quad = l >> 4, r = l & 15;
    const int n0w = wv * 128;                    // 8 waves tile N: wave wv -> n [wv*128, +128)

    // A fragment bases: frag i reads rows m = i*16 + r, k-chunk quad (16B)
    int mbase[4], xm[4];
#pragma unroll
    for (int i = 0; i < 4; i++) {
        int m = i * 16 + r;
        mbase[i] = m * 1024;
        xm[i] = m & 7;
    }
    // B base: frag j reads wt row n = n0w + j*16 + r, bytes kstep*64 + quad*16
    const int8_t* bp = wt + (long)(n0w + r) * K_DIM + quad * 16;

    v4i acc[4][8];
#pragma unroll
    for (int i = 0; i < 4; i++)
#pragma unroll
        for (int j = 0; j < 8; j++) acc[i][j] = (v4i){0, 0, 0, 0};

    v4i breg[2][8];
#pragma unroll
    for (int j = 0; j < 8; j++)
        breg[0][j] = *(const v4i*)(bp + j * 16 * K_DIM);

#pragma unroll
    for (int kt = 0; kt < 16; kt++) {
        if (kt < 15) {
#pragma unroll
            for (int j = 0; j < 8; j++)
                breg[(kt + 1) & 1][j] = *(const v4i*)(bp + j * 16 * K_DIM + (kt + 1) * 64);
        }
        v4i af[4];
#pragma unroll
        for (int i = 0; i < 4; i++) {
            int slot = (kt * 4 + quad) ^ xm[i];
            af[i] = *(const v4i*)(lds_a + mbase[i] + slot * 16);
        }
        __builtin_amdgcn_s_setprio(1);
#pragma unroll
        for (int i = 0; i < 4; i++)
#pragma unroll
            for (int j = 0; j < 8; j++)
                acc[i][j] = __builtin_amdgcn_mfma_i32_16x16x64_i8(
                    af[i], breg[kt & 1][j], acc[i][j], 0, 0, 0);
        __builtin_amdgcn_s_setprio(0);
    }

    // ---- P3: epilogue: y = s * w_scales[n] * (acc - zp * wsum[n]) + bias[n] ----
#pragma unroll
    for (int j = 0; j < 8; j++) {
        int n = n0w + j * 16 + r;
        float sj = s * w_scales[n];
        float cj = zp * (float)wsums[n];
        float bj = bias[n];
#pragma unroll
        for (int i = 0; i < 4; i++) {
            int mrow = m0 + i * 16 + quad * 4;
#pragma unroll
            for (int e = 0; e < 4; e++) {
                out[(long)(mrow + e) * N_DIM + n] = sj * ((float)acc[i][j][e] - cj) + bj;
            }
        }
    }
}

// ---------------- launcher ----------------
extern "C" void kernel_launch(void* const* d_in, const int* in_sizes, int n_in,
                              void* d_out, int out_size, void* d_ws, size_t ws_size,
                              hipStream_t stream) {
    const float* x        = (const float*)d_in[0];
    const int*   w_int8_t = (const int*)d_in[1];   // int8 values widened to int32 by harness
    const float* w_scales = (const float*)d_in[2];
    const int*   w_sums   = (const int*)d_in[3];
    const float* bias     = (const float*)d_in[4];
    float* out = (float*)d_out;

    // ws layout: [0..1023] pmin, [1024..2047] pmax, byte 16384: wt (1 MB)
    float* wsf  = (float*)d_ws;
    float* pmin = wsf;
    float* pmax = wsf + 1024;
    int8_t* wt  = (int8_t*)d_ws + 16384;

    k_prep<<<2048, 256, 0, stream>>>(x, pmin, pmax, w_int8_t, wt);
    k_gemm<<<512, 512, 0, stream>>>(x, wt, pmin, pmax, w_scales, w_sums, bias, out);
}

// Round 6
// 303.371 us; speedup vs baseline: 1.0705x; 1.0705x over previous
//
#include <hip/hip_runtime.h>
#include <stdint.h>

#define M_DIM 32768
#define K_DIM 1024
#define N_DIM 1024

typedef int v4i __attribute__((ext_vector_type(4)));

// ---------------- async global->LDS helper (16B wide) ----------------
__device__ __forceinline__ void gld_lds16(const void* g, void* lds) {
    __builtin_amdgcn_global_load_lds(
        (const __attribute__((address_space(1))) unsigned int*)g,
        (__attribute__((address_space(3))) unsigned int*)lds, 16, 0, 0);
}

// ---------------- kernel 1: fused minmax partials + w transpose ----------------
// blocks 0..1023   : per-block min/max partials over x (32 float4 iters/thread)
// blocks 1024..2047: transpose w [K,N] int32 -> wt [N,K] int8 (32x32 tiles)
__global__ void k_prep(const float* __restrict__ x,
                       float* __restrict__ pmin, float* __restrict__ pmax,
                       const int* __restrict__ w, int8_t* __restrict__ wt) {
    int t = threadIdx.x;
    if (blockIdx.x < 1024) {
        long gid = (long)blockIdx.x * 256 + t;
        const float4* x4 = (const float4*)x;
        const long n4 = (long)M_DIM * K_DIM / 4;  // 8M, exactly 32 iters/thread
        float mn = INFINITY, mx = -INFINITY;
#pragma unroll 4
        for (long i = gid; i < n4; i += 1024 * 256) {
            float4 v = x4[i];
            mn = fminf(mn, fminf(fminf(v.x, v.y), fminf(v.z, v.w)));
            mx = fmaxf(mx, fmaxf(fmaxf(v.x, v.y), fmaxf(v.z, v.w)));
        }
        __shared__ float smn[256], smx[256];
        smn[t] = mn; smx[t] = mx;
        __syncthreads();
        for (int s = 128; s > 0; s >>= 1) {
            if (t < s) {
                smn[t] = fminf(smn[t], smn[t + s]);
                smx[t] = fmaxf(smx[t], smx[t + s]);
            }
            __syncthreads();
        }
        if (t == 0) { pmin[blockIdx.x] = smn[0]; pmax[blockIdx.x] = smx[0]; }
    } else {
        __shared__ int8_t tile[32][33];
        int b = blockIdx.x - 1024;          // 0..1023
        int bn = (b & 31) * 32;             // N tile
        int bk = (b >> 5) * 32;             // K tile
        int tx = t & 31, ty = t >> 5;       // 32x8
#pragma unroll
        for (int i = 0; i < 32; i += 8)
            tile[ty + i][tx] = (int8_t)w[(long)(bk + ty + i) * N_DIM + bn + tx];
        __syncthreads();
#pragma unroll
        for (int i = 0; i < 32; i += 8)
            wt[(long)(bn + ty + i) * K_DIM + bk + tx] = tile[tx][ty + i];
    }
}

// ---------------- kernel 2: finalize (in-block) + quantize x -> int8 ----------------
// Every block re-reduces the 2x1024 partials (8KB, L2-resident) to (scale, zp)
// locally — identical FP result in every block. Block 0 publishes sp for k_gemm.
__device__ __forceinline__ unsigned q4(float4 v, float s, float zp) {
    int a = (int)fminf(fmaxf(rintf(v.x / s) + zp, -128.0f), 127.0f);
    int b = (int)fminf(fmaxf(rintf(v.y / s) + zp, -128.0f), 127.0f);
    int c = (int)fminf(fmaxf(rintf(v.z / s) + zp, -128.0f), 127.0f);
    int d = (int)fminf(fmaxf(rintf(v.w / s) + zp, -128.0f), 127.0f);
    return (a & 255) | ((b & 255) << 8) | ((c & 255) << 16) | ((d & 255) << 24);
}

__global__ void k_quant(const float* __restrict__ x,
                        const float* __restrict__ pmin,
                        const float* __restrict__ pmax,
                        float* __restrict__ sp,
                        int8_t* __restrict__ xq) {
    int t = threadIdx.x;
    float mn = INFINITY, mx = -INFINITY;
#pragma unroll
    for (int i = 0; i < 4; i++) {
        mn = fminf(mn, pmin[i * 256 + t]);
        mx = fmaxf(mx, pmax[i * 256 + t]);
    }
    __shared__ float smn[256], smx[256];
    smn[t] = mn; smx[t] = mx;
    __syncthreads();
    for (int ss = 128; ss > 0; ss >>= 1) {
        if (t < ss) {
            smn[t] = fminf(smn[t], smn[t + ss]);
            smx[t] = fmaxf(smx[t], smx[t + ss]);
        }
        __syncthreads();
    }
    float min_neg = fminf(smn[0], 0.0f);
    float max_pos = fmaxf(smx[0], 0.0f);
    float s = (max_pos - min_neg) / 255.0f;          // IEEE div, matches jnp
    s = fmaxf(s, 1.1920928955078125e-07f);           // np.finfo(f32).eps
    float zp = -128.0f - rintf(min_neg / s);         // rintf = RTNE = jnp.round
    zp = fminf(fmaxf(zp, -128.0f), 127.0f);
    if (blockIdx.x == 0 && t == 0) { sp[0] = s; sp[1] = zp; }

    const float4* x4 = (const float4*)x;
    unsigned* q4out = (unsigned*)xq;
    long base = (long)blockIdx.x * 1024;  // 1024 float4 per block
#pragma unroll
    for (int v = 0; v < 4; v++) {
        long i = base + (long)v * 256 + t;     // lane-contiguous load AND store
        float4 val = x4[i];
        q4out[i] = q4(val, s, zp);
    }
}

// ---------------- kernel 3: int8 GEMM + dequant + bias ----------------
// 128x128 tile per block (4 waves, each 64x64 via 4x4 MFMA 16x16x64 tiles), BK=64.
// 3-STAGE LDS ring (48 KB -> THREE resident blocks/CU), prefetch distance 2:
//   iter kt: wait vmcnt(4) [tile kt+1 stays in flight] -> s_barrier ->
//            STAGE(tile kt+2) -> ds_read buf[kt%3] -> MFMA.
// vs round-3's 4-stage/2-block config: same in-flight depth per wave (~700cy,
// covers L2/HBM latency), but 3 independent blocks/CU -> a block waiting at its
// barrier is covered by the other two computing (TLP absorbs the vmcnt wait).
// Correctness of the single barrier: each wave waits ITS OWN vmcnt(<=4) before
// the barrier, so after the barrier every wave's tile-kt LDS writes have landed;
// a wave's iter-(kt-1) ds_reads are lgkmcnt-complete before its MFMAs, hence
// before it reaches barrier kt, so the STAGE at kt may overwrite buf[(kt+2)%3].
// LDS layout: [row][64 bytes] with XOR swizzle on 16B quads:
//   slot s in row m holds global quad q = s ^ (m&3) ^ ((m>>2)&3)
// XCD-bijective block swizzle: the 8 N-blocks sharing an A panel run on ONE XCD.
__global__ __launch_bounds__(256, 3) void k_gemm(
    const int8_t* __restrict__ xq, const int8_t* __restrict__ wt,
    const float* __restrict__ sp, const float* __restrict__ w_scales,
    const int* __restrict__ wsums, const float* __restrict__ bias,
    float* __restrict__ out) {
    __shared__ __align__(16) int8_t lds_a[3][128 * 64];   // 24 KB
    __shared__ __align__(16) int8_t lds_b[3][128 * 64];   // 24 KB

    const int t = threadIdx.x;
    const int orig = blockIdx.x;
    const int swz = (orig & 7) * 256 + (orig >> 3);  // nwg=2048, %8==0 -> bijective
    const int m0 = (swz >> 3) * 128;   // 0..255
    const int n0 = (swz & 7) * 128;    // 0..7
    const int w = t >> 6, l = t & 63, quad = l >> 4, r = l & 15;
    const int wave_m = (w & 1) * 64, wave_n = (w >> 1) * 64;

    v4i acc[4][4];
#pragma unroll
    for (int i = 0; i < 4; i++)
#pragma unroll
        for (int j = 0; j < 4; j++) acc[i][j] = (v4i){0, 0, 0, 0};

    // staging: 2 slots per thread per operand; slot -> (row, swizzled global quad)
    const int slot0 = t, slot1 = 256 + t;
    const int row0 = slot0 >> 2, s0 = slot0 & 3;
    const int row1 = slot1 >> 2, s1 = slot1 & 3;
    const int q0 = s0 ^ (row0 & 3) ^ ((row0 >> 2) & 3);
    const int q1 = s1 ^ (row1 & 3) ^ ((row1 >> 2) & 3);
    const int8_t* gA0 = xq + (long)(m0 + row0) * K_DIM + q0 * 16;
    const int8_t* gA1 = xq + (long)(m0 + row1) * K_DIM + q1 * 16;
    const int8_t* gB0 = wt + (long)(n0 + row0) * K_DIM + q0 * 16;
    const int8_t* gB1 = wt + (long)(n0 + row1) * K_DIM + q1 * 16;

#define STAGE(buf, kb)                                        \
    do {                                                      \
        gld_lds16(gA0 + (kb), lds_a[buf] + slot0 * 16);       \
        gld_lds16(gA1 + (kb), lds_a[buf] + slot1 * 16);       \
        gld_lds16(gB0 + (kb), lds_b[buf] + slot0 * 16);       \
        gld_lds16(gB1 + (kb), lds_b[buf] + slot1 * 16);       \
    } while (0)

    // LDS read addresses (per-lane fragment reads, swizzle-corrected)
    int ra[4], rb[4];
#pragma unroll
    for (int i = 0; i < 4; i++) {
        int mrow = wave_m + i * 16 + r;
        int sa = quad ^ (mrow & 3) ^ ((mrow >> 2) & 3);
        ra[i] = mrow * 64 + sa * 16;
        int nrow = wave_n + i * 16 + r;
        int sb = quad ^ (nrow & 3) ^ ((nrow >> 2) & 3);
        rb[i] = nrow * 64 + sb * 16;
    }

    // prologue: fill ring 2 deep (8 loads in flight)
    STAGE(0, 0);
    STAGE(1, 64);

#pragma unroll
    for (int kt = 0; kt < 16; ++kt) {
        // tile kt's 4 loads must be complete; tile kt+1 stays in flight
        if (kt < 15)
            asm volatile("s_waitcnt vmcnt(4)" ::: "memory");
        else
            asm volatile("s_waitcnt vmcnt(0)" ::: "memory");
        asm volatile("s_barrier" ::: "memory");   // all threads' tile-kt loads done;
                                                  // also: everyone finished reading
                                                  // buf[(kt+2)%3] (= tile kt-1's buf)

        if (kt <= 13) STAGE((kt + 2) % 3, (kt + 2) * 64);  // depth-2 prefetch

        v4i af[4], bf[4];
#pragma unroll
        for (int i = 0; i < 4; i++) af[i] = *(const v4i*)(lds_a[kt % 3] + ra[i]);
#pragma unroll
        for (int j = 0; j < 4; j++) bf[j] = *(const v4i*)(lds_b[kt % 3] + rb[j]);

        __builtin_amdgcn_s_setprio(1);
#pragma unroll
        for (int i = 0; i < 4; i++)
#pragma unroll
            for (int j = 0; j < 4; j++)
                acc[i][j] = __builtin_amdgcn_mfma_i32_16x16x64_i8(af[i], bf[j], acc[i][j], 0, 0, 0);
        __builtin_amdgcn_s_setprio(0);
    }
#undef STAGE

    // epilogue: y = x_scale * w_scales[n] * (acc - x_zp * wsum[n]) + bias[n]
    const float scale = sp[0], zp = sp[1];
#pragma unroll
    for (int j = 0; j < 4; j++) {
        int n = n0 + wave_n + j * 16 + r;
        float sj = scale * w_scales[n];
        float cj = zp * (float)wsums[n];
        float bj = bias[n];
#pragma unroll
        for (int i = 0; i < 4; i++) {
            int mbase = m0 + wave_m + i * 16 + quad * 4;
#pragma unroll
            for (int e = 0; e < 4; e++) {
                out[(long)(mbase + e) * N_DIM + n] = sj * ((float)acc[i][j][e] - cj) + bj;
            }
        }
    }
}

// ---------------- launcher ----------------
extern "C" void kernel_launch(void* const* d_in, const int* in_sizes, int n_in,
                              void* d_out, int out_size, void* d_ws, size_t ws_size,
                              hipStream_t stream) {
    const float* x        = (const float*)d_in[0];
    const int*   w_int8_t = (const int*)d_in[1];   // int8 values widened to int32 by harness
    const float* w_scales = (const float*)d_in[2];
    const int*   w_sums   = (const int*)d_in[3];
    const float* bias     = (const float*)d_in[4];
    float* out = (float*)d_out;

    // ws layout: [0..1023] pmin, [1024..2047] pmax, [2048..2049] (scale,zp),
    // byte 16384: wt (1 MB), byte 16384+1MB: xq (32 MB)
    float* wsf  = (float*)d_ws;
    float* pmin = wsf;
    float* pmax = wsf + 1024;
    float* sp   = wsf + 2048;
    int8_t* wt  = (int8_t*)d_ws + 16384;
    int8_t* xq  = (int8_t*)d_ws + 16384 + (size_t)K_DIM * N_DIM;

    k_prep<<<2048, 256, 0, stream>>>(x, pmin, pmax, w_int8_t, wt);
    k_quant<<<8192, 256, 0, stream>>>(x, pmin, pmax, sp, xq);
    k_gemm<<<2048, 256, 0, stream>>>(xq, wt, sp, w_scales, w_sums, bias, out);
}